// Round 7
// baseline (138.299 us; speedup 1.0000x reference)
//
#include <hip/hip_runtime.h>
#include <stdint.h>

#define BATCH 8
#define HIN   28
#define CH    32
#define HO    14
#define NIN   784   // 28*28
#define NOUT  196   // 14*14

#define NITEM  (4 * NIN * 8)      // 25088 16B-items per block
#define ITERS  (NITEM / 256)      // 98 per thread
#define UNROLL 7
#define OUTER  (ITERS / UNROLL)   // 14
#define TILE_W (NOUT * CH)        // 6272 words

typedef float f32x4 __attribute__((ext_vector_type(4)));

// One workgroup per (b, p).
// Phase 0: per-window argmax codes for all windows of image b (L2-hot mu);
//          each (q,half) thread writes its 4 cmq entries directly:
//          cmq[j][half] = (q*CH)<<16 | mask16 of channels selecting j.
//          Own-p threads also write mu_out. No colmask array (LDS 31.6KB ->
//          5 blocks/CU).
// Phase 1: selective stream with PIPELINED masks: addresses are pure counter
//          functions; the cmq word for each item is prefetched one iteration
//          ahead into registers, so sel->address cndmask resolves ~500cy
//          before the load issues (no ds_read->load critical path). Lanes
//          whose 16B chunk is unselected redirect to a dummy base: expected
//          fetch 0.64x of dense at 64B grain. 7 loads in flight per wave.
//          Branchless LDS scatter (real slot or per-lane trash slot).
// Phase 2: 25KB tile -> global, fully coalesced, nontemporal.
// Each output word written exactly once (unique (r,dj) per channel):
// no init, no atomics, deterministic.
__global__ __launch_bounds__(256, 5) void vdp_pool_fused_kernel(
        const float* __restrict__ mu_in,
        const float* __restrict__ sigma_in,
        float* __restrict__ mu_out,
        float* __restrict__ sigma_out)
{
    __shared__ __align__(16) float out_tile[TILE_W + 64];  // +64 trash words
    __shared__ uint32_t cmq[NIN * 2];                      // [j][half]

    const int blk = blockIdx.x;                // b*NOUT + p
    const int b   = blk / NOUT;
    const int p   = blk - b * NOUT;
    const int tid = threadIdx.x;

    // ---------------- Phase 0: window codes -> cmq (+ mu_out for own p) ----
    for (int w = tid; w < NOUT * 2; w += 256) {
        const int q2   = w >> 1;
        const int hf   = w & 1;
        const int qy = q2 / HO, qx = q2 - qy * HO;
        const float* base =
            mu_in + (((size_t)b * HIN + 2 * qy) * HIN + 2 * qx) * CH + hf * 16;

        uint32_t kqh = 0;
        #pragma unroll
        for (int g = 0; g < 4; ++g) {
            const float4 v0 = *(const float4*)(base + g * 4);
            const float4 v1 = *(const float4*)(base + CH + g * 4);
            const float4 v2 = *(const float4*)(base + HIN * CH + g * 4);
            const float4 v3 = *(const float4*)(base + HIN * CH + CH + g * 4);
            float m0, m1, m2, m3;
            uint32_t k0, k1, k2, k3;
            { float best = v0.x; uint32_t k = 0;
              if (v1.x > best) { best = v1.x; k = 1; }
              if (v2.x > best) { best = v2.x; k = 2; }
              if (v3.x > best) { best = v3.x; k = 3; }
              m0 = best; k0 = k; }
            { float best = v0.y; uint32_t k = 0;
              if (v1.y > best) { best = v1.y; k = 1; }
              if (v2.y > best) { best = v2.y; k = 2; }
              if (v3.y > best) { best = v3.y; k = 3; }
              m1 = best; k1 = k; }
            { float best = v0.z; uint32_t k = 0;
              if (v1.z > best) { best = v1.z; k = 1; }
              if (v2.z > best) { best = v2.z; k = 2; }
              if (v3.z > best) { best = v3.z; k = 3; }
              m2 = best; k2 = k; }
            { float best = v0.w; uint32_t k = 0;
              if (v1.w > best) { best = v1.w; k = 1; }
              if (v2.w > best) { best = v2.w; k = 2; }
              if (v3.w > best) { best = v3.w; k = 3; }
              m3 = best; k3 = k; }
            kqh |= (k0 << (2 * (g * 4 + 0))) | (k1 << (2 * (g * 4 + 1))) |
                   (k2 << (2 * (g * 4 + 2))) | (k3 << (2 * (g * 4 + 3)));
            if (q2 == p) {
                *(float4*)(mu_out + (size_t)blk * CH + hf * 16 + g * 4) =
                    make_float4(m0, m1, m2, m3);
            }
        }
        const uint32_t qb = (uint32_t)(q2 * CH) << 16;
        const uint32_t jb = (uint32_t)(2 * qy) * HIN + 2u * qx;
        #pragma unroll
        for (int dj = 0; dj < 4; ++dj) {
            uint32_t m = 0;
            #pragma unroll
            for (int cl = 0; cl < 16; ++cl)
                m |= (((kqh >> (2 * cl)) & 3u) == (uint32_t)dj) ? (1u << cl) : 0u;
            const uint32_t j = jb + (uint32_t)(dj >> 1) * HIN + (dj & 1);
            cmq[j * 2 + hf] = qb | m;
        }
    }
    __syncthreads();

    // ---------------- per-thread constants + row masks from cmq ------------
    const uint32_t half = ((uint32_t)tid >> 2) & 1u;
    const uint32_t shs  = ((uint32_t)tid & 3u) * 4u;   // sub*4
    const uint32_t hs   = half * 16u + shs;
    const int py = p / HO, px = p - py * HO;
    const uint32_t ibase = (uint32_t)(2 * py) * HIN + 2u * px;

    unsigned long long rmpack = 0ull;                  // 4 x 16-bit row masks
    #pragma unroll
    for (int r = 0; r < 4; ++r) {
        const uint32_t jp = ibase + (uint32_t)(r >> 1) * HIN + (r & 1);
        rmpack |= (unsigned long long)(cmq[jp * 2 + half] & 0xFFFFu) << (16 * r);
    }

    // ---------------- Phase 1: pipelined selective stream ------------------
    const float* sb = sigma_in + (size_t)b * NIN * NIN * CH;
    const uint32_t rjb   = (uint32_t)tid >> 3;         // 8 lanes per (r,j) row
    const uint32_t trash = TILE_W + ((uint32_t)tid & 63u);

    uint32_t tab[UNROLL];                              // masks for iter o
    #pragma unroll
    for (int u = 0; u < UNROLL; ++u) {
        const uint32_t rj = rjb + (uint32_t)u * 32u;
        const uint32_t r  = rj / NIN;
        const uint32_t j  = rj - r * NIN;
        tab[u] = cmq[j * 2 + half];
    }

    for (int o = 0; o < OUTER; ++o) {
        f32x4    val[UNROLL];
        uint32_t off[UNROLL];
        uint32_t s4p[UNROLL];
        // issue loads for iter o (masks already in regs)
        #pragma unroll
        for (int u = 0; u < UNROLL; ++u) {
            const uint32_t rj = rjb + (uint32_t)(o * UNROLL + u) * 32u;
            const uint32_t r  = rj / NIN;
            const uint32_t j  = rj - r * NIN;
            const uint32_t i  = ibase + (r >> 1) * HIN + (r & 1u);
            const uint32_t sel16 =
                ((uint32_t)(rmpack >> (r * 16u)) & tab[u]) & 0xFFFFu;
            const float* a = sb + (((size_t)i * NIN + j) << 5) + hs;
            val[u] = __builtin_nontemporal_load(
                (const f32x4*)(sel16 ? a : (sb + hs)));
            off[u] = (tab[u] >> 16) + hs;
            s4p[u] = (sel16 >> shs) & 0xFu;
        }
        // prefetch masks for iter o+1 (hidden under the in-flight loads)
        if (o + 1 < OUTER) {
            #pragma unroll
            for (int u = 0; u < UNROLL; ++u) {
                const uint32_t rj = rjb + (uint32_t)((o + 1) * UNROLL + u) * 32u;
                const uint32_t r  = rj / NIN;
                const uint32_t j  = rj - r * NIN;
                tab[u] = cmq[j * 2 + half];
            }
        }
        // branchless scatter of iter o
        #pragma unroll
        for (int u = 0; u < UNROLL; ++u) {
            const uint32_t s4 = s4p[u], bs = off[u];
            out_tile[(s4 & 1u) ? bs + 0u : trash] = val[u][0];
            out_tile[(s4 & 2u) ? bs + 1u : trash] = val[u][1];
            out_tile[(s4 & 4u) ? bs + 2u : trash] = val[u][2];
            out_tile[(s4 & 8u) ? bs + 3u : trash] = val[u][3];
        }
    }
    __syncthreads();

    // ---------------- Phase 2: coalesced nontemporal tile write-out --------
    {
        const f32x4* srcT = (const f32x4*)out_tile;
        f32x4* dstT = (f32x4*)(sigma_out + (size_t)blk * TILE_W);
        for (int w = tid; w < TILE_W / 4; w += 256)    // 1568 f32x4
            __builtin_nontemporal_store(srcT[w], &dstT[w]);
    }
}

extern "C" void kernel_launch(void* const* d_in, const int* in_sizes, int n_in,
                              void* d_out, int out_size, void* d_ws, size_t ws_size,
                              hipStream_t stream) {
    const float* mu_in    = (const float*)d_in[0];
    const float* sigma_in = (const float*)d_in[1];

    float* mu_out    = (float*)d_out;                      // 8*14*14*32 floats
    float* sigma_out = (float*)d_out + BATCH * NOUT * CH;  // 8*196*196*32 floats

    vdp_pool_fused_kernel<<<BATCH * NOUT, 256, 0, stream>>>(
        mu_in, sigma_in, mu_out, sigma_out);
}